// Round 9
// baseline (142.004 us; speedup 1.0000x reference)
//
#include <hip/hip_runtime.h>
#include <math.h>

// SVD++ scoring, R8: inline-asm-forced 16-deep gather batch (R7 + early-clobber fix).
// R7 aborted: outputs were "=v" (no early-clobber), so the allocator could
// overlap a load's destination with a later load's address pair -> wild
// address -> GPU fault. "=&v" forces disjoint outputs.
// One 64-lane wave per batch element b. sub = lane>>4 (row group),
// l16 = lane&15 (float4 within the 256B row).
// Per 64-row chunk: ONE coalesced load of 64 indices -> __shfl distribution
// -> ONE asm volatile block with 16 literal global_load_dwordx4 + final
// s_waitcnt vmcnt(0). 16KB per wave verifiably in flight (R2-R6 were all
// silently strip-mined to ~8-deep; VGPR<=60 was the tell).
// dot(u + summed/norm, i) = u·i + (summed·i)/norm -> scalar wave reductions.

#define WAVES_PER_BLOCK 4

#define ADDR(d) const float* p##d = imp_emb +                            \
    (size_t)__shfl(my_idx, 4*(d) + sub, 64) * 64 + l16 * 4;
#define GLD(d) "global_load_dwordx4 %[o" #d "], %[p" #d "], off\n\t"
#define ACCUM(d)                                                         \
    if (super + 4*(d) + sub < end) {                                     \
        acc.x += v##d.x; acc.y += v##d.y;                                \
        acc.z += v##d.z; acc.w += v##d.w;                                \
    }

__global__ __launch_bounds__(256, 1) void svdpp_kernel(
    const int* __restrict__ user_ids,
    const int* __restrict__ item_ids,
    const int* __restrict__ offsets,
    const int* __restrict__ flat_implicit,
    const float* __restrict__ user_emb,
    const float* __restrict__ item_emb,
    const float* __restrict__ imp_emb,
    const float* __restrict__ user_bias,
    const float* __restrict__ item_bias,
    const float* __restrict__ global_bias,
    float* __restrict__ out,
    int B, int N)
{
    const int wave = threadIdx.x >> 6;
    const int lane = threadIdx.x & 63;
    const int b = blockIdx.x * WAVES_PER_BLOCK + wave;
    if (b >= B) return;

    const int sub = lane >> 4;   // 0..3: which row this lane helps load
    const int l16 = lane & 15;   // 0..15: which float4 of the row

    const int start = offsets[b];
    const int end   = (b + 1 < B) ? offsets[b + 1] : N;
    const int n     = end - start;

    const int user = user_ids[b];
    const int item = item_ids[b];

    // item-embedding fragment for this lane's 4 columns (broadcast across subs)
    const float4 i4 = ((const float4*)(item_emb + (size_t)item * 64))[l16];

    float4 acc = make_float4(0.f, 0.f, 0.f, 0.f);

    // 64 rows per chunk; sub-group `sub` handles rows super + 4*d + sub,
    // d = 0..15. Out-of-range slots read a safe index (flat_implicit[start])
    // and are masked out of the accumulate.
    for (int super = start; super < end; super += 64) {
        const int a = super + lane;
        const int my_idx = flat_implicit[(a < end) ? a : start];

        ADDR(0)  ADDR(1)  ADDR(2)  ADDR(3)
        ADDR(4)  ADDR(5)  ADDR(6)  ADDR(7)
        ADDR(8)  ADDR(9)  ADDR(10) ADDR(11)
        ADDR(12) ADDR(13) ADDR(14) ADDR(15)

        float4 v0, v1, v2, v3, v4, v5, v6, v7;
        float4 v8, v9, v10, v11, v12, v13, v14, v15;

        // 16 loads issue back-to-back, then one drain — not schedulable.
        // "=&v" (early-clobber): outputs must not overlap the address pairs.
        asm volatile(
            GLD(0)  GLD(1)  GLD(2)  GLD(3)
            GLD(4)  GLD(5)  GLD(6)  GLD(7)
            GLD(8)  GLD(9)  GLD(10) GLD(11)
            GLD(12) GLD(13) GLD(14) GLD(15)
            "s_waitcnt vmcnt(0)\n\t"
            : [o0] "=&v"(v0),  [o1] "=&v"(v1),  [o2] "=&v"(v2),  [o3] "=&v"(v3),
              [o4] "=&v"(v4),  [o5] "=&v"(v5),  [o6] "=&v"(v6),  [o7] "=&v"(v7),
              [o8] "=&v"(v8),  [o9] "=&v"(v9),  [o10]"=&v"(v10), [o11]"=&v"(v11),
              [o12]"=&v"(v12), [o13]"=&v"(v13), [o14]"=&v"(v14), [o15]"=&v"(v15)
            : [p0] "v"(p0),  [p1] "v"(p1),  [p2] "v"(p2),  [p3] "v"(p3),
              [p4] "v"(p4),  [p5] "v"(p5),  [p6] "v"(p6),  [p7] "v"(p7),
              [p8] "v"(p8),  [p9] "v"(p9),  [p10]"v"(p10), [p11]"v"(p11),
              [p12]"v"(p12), [p13]"v"(p13), [p14]"v"(p14), [p15]"v"(p15)
            : "memory");

        ACCUM(0)  ACCUM(1)  ACCUM(2)  ACCUM(3)
        ACCUM(4)  ACCUM(5)  ACCUM(6)  ACCUM(7)
        ACCUM(8)  ACCUM(9)  ACCUM(10) ACCUM(11)
        ACCUM(12) ACCUM(13) ACCUM(14) ACCUM(15)
    }

    // partial of summed·i (reduce over all 64 lanes: subs × columns)
    float ds = acc.x * i4.x + acc.y * i4.y + acc.z * i4.z + acc.w * i4.w;

    // partial of u·i: one column per lane
    const float u_c = user_emb[(size_t)user * 64 + lane];
    const float i_c = item_emb[(size_t)item * 64 + lane];
    float dui = u_c * i_c;

    // wave-wide butterfly reduction of both scalars
    #pragma unroll
    for (int off = 32; off >= 1; off >>= 1) {
        ds  += __shfl_xor(ds,  off, 64);
        dui += __shfl_xor(dui, off, 64);
    }

    if (lane == 0) {
        const float norm = (n > 0) ? sqrtf((float)n) : 1.0f;
        out[b] = dui + ds / norm + user_bias[user] + item_bias[item]
               + global_bias[0];
    }
}

extern "C" void kernel_launch(void* const* d_in, const int* in_sizes, int n_in,
                              void* d_out, int out_size, void* d_ws, size_t ws_size,
                              hipStream_t stream) {
    const int*   user_ids      = (const int*)  d_in[0];
    const int*   item_ids      = (const int*)  d_in[1];
    const int*   offsets       = (const int*)  d_in[2];
    const int*   flat_implicit = (const int*)  d_in[3];
    const float* user_emb      = (const float*)d_in[4];
    const float* item_emb      = (const float*)d_in[5];
    const float* imp_emb       = (const float*)d_in[6];
    const float* user_bias     = (const float*)d_in[7];
    const float* item_bias     = (const float*)d_in[8];
    const float* global_bias   = (const float*)d_in[9];
    float* out = (float*)d_out;

    const int B = in_sizes[0];
    const int N = in_sizes[3];

    const int grid = (B + WAVES_PER_BLOCK - 1) / WAVES_PER_BLOCK;
    svdpp_kernel<<<grid, WAVES_PER_BLOCK * 64, 0, stream>>>(
        user_ids, item_ids, offsets, flat_implicit,
        user_emb, item_emb, imp_emb,
        user_bias, item_bias, global_bias,
        out, B, N);
}